// Round 7
// baseline (936.977 us; speedup 1.0000x reference)
//
#include <hip/hip_runtime.h>

// Sinkhorn, N=4096, D=2, P=1, eps=0.1, 50 iters — persistent cooperative kernel.
// Round-10: round-8 baseline (577 us profiled, VERIFIED; r9 pin reverted — it
// parked Dreg in AGPRs, VGPR stayed 64, dur flat). Two serial-chain cuts:
//  1. Combine folded into barrier entry: after the post-reduce __syncthreads,
//     wave 0 (tids 0-15) combines + coh_stores u/v rows; tid 0 then drains
//     with a WAVE-level s_waitcnt vmcnt(0) (covers all 16 stores — same wave)
//     and does arrival+poll inline. Removes one block-wide __syncthreads and
//     the block-wide vmcnt drain (4 -> 3 syncs/phase).
//  2. Barrier polls the 16 leaf COUNTERS directly (all >= 16k, monotone,
//     ABA-free) — removes the leafdone-store MALL round-trip.
//  3. micro: u = A_LOGMU - INV_SL*log2(S) (eps*ln S == eps*ln2*log2 S).
// stageW, stageCoords, Dreg precompute, phase math, epilogue: verbatim r8.

#define NPTS    4096
#define EPS_F   0.1f
#define S_L2E   14.426950408889634f     /* log2(e)/eps */
#define INV_SL  0.0693147180559945f     /* 1/S_L2E = eps*ln2 */
#define A_LOGMU (-0.8317725207f)        /* eps * ln(1/N + 1e-8) */
#define N_ITER  50
#define NBLK    256
#define TPB     1024
#define WPB     (TPB / 64)              /* 16 waves/block */
#define RPW     2                       /* rows per wave (wave-pair shares rows) */
#define HALFC   2048                    /* columns per wave (pair splits 4096) */
#define NJT     (HALFC / 256)           /* 8 j-tiles of 64 lanes x 4 cols */
#define NLEAF   16
#define BSTRIDE 64                      /* ints between barrier words = 256 B */
#define BAR_INTS (NLEAF * BSTRIDE)      /* 16 leaf counters, 256 B apart */

typedef float f4u __attribute__((ext_vector_type(4), aligned(4)));

__device__ __forceinline__ float fexp2(float x) {
#if __has_builtin(__builtin_amdgcn_exp2f)
  return __builtin_amdgcn_exp2f(x);
#else
  float r;
  asm("v_exp_f32 %0, %1" : "=v"(r) : "v"(x));
  return r;
#endif
}

__device__ __forceinline__ float coh_load(const float* p) {
  return __hip_atomic_load(p, __ATOMIC_RELAXED, __HIP_MEMORY_SCOPE_AGENT);
}
__device__ __forceinline__ void coh_store(float* p, float x) {
  __hip_atomic_store(p, x, __ATOMIC_RELAXED, __HIP_MEMORY_SCOPE_AGENT);
}

__device__ __forceinline__ float wave_sum64(float x) {
#pragma unroll
  for (int off = 32; off > 0; off >>= 1) x += __shfl_xor(x, off, 64);
  return x;
}

// Combine + output store + grid barrier, fused.
// Entry __syncthreads makes sPart visible (and all waves done reading sW).
// Wave 0: tids 0-15 combine and coh_store the block's 16 u/v rows; tid 0 then
// drains the wave's stores (wave-level vmcnt(0) covers all 16 — same wave),
// RMW-arrives on its leaf line, and polls all 16 leaf counters for >= 16k
// (monotone counters: a block racing ahead only pushes counts higher; >= is
// exact, ABA-free). Exit __syncthreads releases the block.
__device__ __forceinline__ void combine_store_barrier(
    float (*sPart)[RPW], float* __restrict__ wout, int row0blk, int tid,
    int* __restrict__ bar, int k) {
  __syncthreads();
  if (tid < 16) {
    const int p = tid >> 1, r = tid & 1;
    const float S = sPart[2 * p][r] + sPart[2 * p + 1][r];
    coh_store(wout + row0blk + p * RPW + r, A_LOGMU - INV_SL * __log2f(S));
    if (tid == 0) {
      asm volatile("s_waitcnt vmcnt(0)" ::: "memory");
      const int myleaf = blockIdx.x & (NLEAF - 1);
      __hip_atomic_fetch_add(bar + myleaf * BSTRIDE, 1, __ATOMIC_RELAXED,
                             __HIP_MEMORY_SCOPE_AGENT);
      const int want = NLEAF * k;
      for (;;) {
        int mn = 0x7fffffff;
#pragma unroll
        for (int rr = 0; rr < NLEAF; ++rr) {
          const int f = __hip_atomic_load(bar + rr * BSTRIDE, __ATOMIC_RELAXED,
                                          __HIP_MEMORY_SCOPE_AGENT);
          mn = min(mn, f);
        }
        if (mn >= want) break;
        __builtin_amdgcn_s_sleep(1);
      }
    }
  }
  __syncthreads();
}

// Per-phase stage: coherent W load + scale into LDS (coords are persistent).
__device__ __forceinline__ void stageW(const float* __restrict__ win,
                                       float* __restrict__ sW, int tid) {
  const int c = tid * 4;
  const float w0 = coh_load(win + c + 0), w1 = coh_load(win + c + 1);
  const float w2 = coh_load(win + c + 2), w3 = coh_load(win + c + 3);
  float4 W;
  W.x = w0 * S_L2E;  W.y = w1 * S_L2E;  W.z = w2 * S_L2E;  W.w = w3 * S_L2E;
  *(float4*)(sW + c) = W;
  __syncthreads();
}

// One-time coord stage: scaled column coords into LDS (4 cols/thread).
__device__ __forceinline__ void stageCoords(const float* __restrict__ colp,
                                            float* __restrict__ sC0,
                                            float* __restrict__ sC1, int tid) {
  const int c = tid * 4;
  const float4 a = ((const float4*)colp)[(c >> 1) + 0];  // (x0,y0,x1,y1)
  const float4 b = ((const float4*)colp)[(c >> 1) + 1];  // (x2,y2,x3,y3)
  float4 C0, C1;
  C0.x = a.x * S_L2E; C0.y = a.z * S_L2E; C0.z = b.x * S_L2E; C0.w = b.z * S_L2E;
  C1.x = a.y * S_L2E; C1.y = a.w * S_L2E; C1.z = b.y * S_L2E; C1.w = b.w * S_L2E;
  *(float4*)(sC0 + c) = C0;
  *(float4*)(sC1 + c) = C1;
}

// u-phase: W from LDS, D from Dreg (compiler may remat — measured-neutral).
__device__ __forceinline__ void phaseU(const float* __restrict__ sW,
                                       const float (&Dreg)[NJT][RPW][4],
                                       float (*sPart)[RPW],
                                       float* __restrict__ wout,
                                       int row0blk, int wv, int lane, int tid,
                                       int base, int* __restrict__ bar, int k) {
  float acc0 = 0.f, acc1 = 0.f;
#pragma unroll
  for (int jt = 0; jt < NJT; ++jt) {
    const int j = base + jt * 256;
    const float4 W = *(const float4*)(sW + j);
    acc0 += (fexp2(W.x - Dreg[jt][0][0]) + fexp2(W.y - Dreg[jt][0][1])) +
            (fexp2(W.z - Dreg[jt][0][2]) + fexp2(W.w - Dreg[jt][0][3]));
    acc1 += (fexp2(W.x - Dreg[jt][1][0]) + fexp2(W.y - Dreg[jt][1][1])) +
            (fexp2(W.z - Dreg[jt][1][2]) + fexp2(W.w - Dreg[jt][1][3]));
  }
  const float S0 = wave_sum64(acc0);
  const float S1 = wave_sum64(acc1);
  if (lane == 0) { sPart[wv][0] = S0; sPart[wv][1] = S1; }
  combine_store_barrier(sPart, wout, row0blk, tid, bar, k);
}

// v-phase: distances recomputed from persistent x-coords in LDS.
__device__ __forceinline__ void phaseV(const float* __restrict__ rx,
                                       const float* __restrict__ ry,
                                       const float* __restrict__ sW,
                                       const float* __restrict__ sC0,
                                       const float* __restrict__ sC1,
                                       float (*sPart)[RPW],
                                       float* __restrict__ wout,
                                       int row0blk, int wv, int lane, int tid,
                                       int base, int* __restrict__ bar, int k) {
  float acc0 = 0.f, acc1 = 0.f;
#pragma unroll
  for (int jt = 0; jt < NJT; ++jt) {
    const int j = base + jt * 256;
    const float4 W  = *(const float4*)(sW + j);
    const float4 C0 = *(const float4*)(sC0 + j);
    const float4 C1 = *(const float4*)(sC1 + j);
    {
      const float a0 = (W.x - fabsf(rx[0] - C0.x)) - fabsf(ry[0] - C1.x);
      const float a1 = (W.y - fabsf(rx[0] - C0.y)) - fabsf(ry[0] - C1.y);
      const float a2 = (W.z - fabsf(rx[0] - C0.z)) - fabsf(ry[0] - C1.z);
      const float a3 = (W.w - fabsf(rx[0] - C0.w)) - fabsf(ry[0] - C1.w);
      acc0 += (fexp2(a0) + fexp2(a1)) + (fexp2(a2) + fexp2(a3));
    }
    {
      const float a0 = (W.x - fabsf(rx[1] - C0.x)) - fabsf(ry[1] - C1.x);
      const float a1 = (W.y - fabsf(rx[1] - C0.y)) - fabsf(ry[1] - C1.y);
      const float a2 = (W.z - fabsf(rx[1] - C0.z)) - fabsf(ry[1] - C1.z);
      const float a3 = (W.w - fabsf(rx[1] - C0.w)) - fabsf(ry[1] - C1.w);
      acc1 += (fexp2(a0) + fexp2(a1)) + (fexp2(a2) + fexp2(a3));
    }
  }
  const float S0 = wave_sum64(acc0);
  const float S1 = wave_sum64(acc1);
  if (lane == 0) { sPart[wv][0] = S0; sPart[wv][1] = S1; }
  combine_store_barrier(sPart, wout, row0blk, tid, bar, k);
}

__global__ void __launch_bounds__(TPB, 4)
sinkhorn_main(const float* __restrict__ x, const float* __restrict__ y,
              float* __restrict__ u, float* __restrict__ v,
              float* __restrict__ out, int* __restrict__ bar) {
  __shared__ float sW[NPTS];
  __shared__ float sC0y[NPTS], sC1y[NPTS];    // y cols (u-phase precompute/epi)
  __shared__ float sC0x[NPTS], sC1x[NPTS];    // x cols (v-phase)
  __shared__ float sPart[WPB][RPW];
  __shared__ float sCost[WPB];

  const int tid  = threadIdx.x;
  const int wv   = tid >> 6;
  const int lane = tid & 63;
  const int row0blk = blockIdx.x * (WPB / 2) * RPW;        // 16 rows per block
  const int row0 = row0blk + (wv >> 1) * RPW;              // this wave's rows
  const int base = (wv & 1) * HALFC + lane * 4;

  float rxu[RPW], ryu[RPW], rxv[RPW], ryv[RPW];
#pragma unroll
  for (int r = 0; r < RPW; ++r) {
    const float2 xr = ((const float2*)x)[row0 + r];
    const float2 yr = ((const float2*)y)[row0 + r];
    rxu[r] = xr.x * S_L2E;  ryu[r] = xr.y * S_L2E;
    rxv[r] = yr.x * S_L2E;  ryv[r] = yr.y * S_L2E;
  }

  stageCoords(y, sC0y, sC1y, tid);
  stageCoords(x, sC0x, sC1x, tid);
  __syncthreads();

  // Iteration-invariant scaled distances for this thread's u-phase footprint.
  float Dreg[NJT][RPW][4];
#pragma unroll
  for (int jt = 0; jt < NJT; ++jt) {
    const int j = base + jt * 256;
    const float4 C0 = *(const float4*)(sC0y + j);
    const float4 C1 = *(const float4*)(sC1y + j);
#pragma unroll
    for (int r = 0; r < RPW; ++r) {
      Dreg[jt][r][0] = fabsf(rxu[r] - C0.x) + fabsf(ryu[r] - C1.x);
      Dreg[jt][r][1] = fabsf(rxu[r] - C0.y) + fabsf(ryu[r] - C1.y);
      Dreg[jt][r][2] = fabsf(rxu[r] - C0.z) + fabsf(ryu[r] - C1.z);
      Dreg[jt][r][3] = fabsf(rxu[r] - C0.w) + fabsf(ryu[r] - C1.w);
    }
  }

  int k = 0;
  for (int it = 0; it < N_ITER; ++it) {
    stageW(v, sW, tid);                                     // win = v
    phaseU(sW, Dreg, sPart, u, row0blk, wv, lane, tid, base, bar, ++k);
    stageW(u, sW, tid);                                     // win = u
    phaseV(rxv, ryv, sW, sC0x, sC1x, sPart, v, row0blk, wv, lane, tid, base,
           bar, ++k);
  }
  stageW(v, sW, tid);                                       // final v

  // ---- output: out[0]=cost, out[1..]=pi, out[1+N*N..]=C ----
  float* __restrict__ pi = out + 1;
  float* __restrict__ cm = out + 1 + (size_t)NPTS * NPTS;
  float uu[RPW];
#pragma unroll
  for (int r = 0; r < RPW; ++r) uu[r] = coh_load(u + row0 + r) * S_L2E;

  float costacc = 0.f;
#pragma unroll
  for (int jt = 0; jt < NJT; ++jt) {          // full unroll: Dreg idx static
    const int j = base + jt * 256;
    const float4 W = *(const float4*)(sW + j);
#pragma unroll
    for (int r = 0; r < RPW; ++r) {
      const float s0 = Dreg[jt][r][0];
      const float s1 = Dreg[jt][r][1];
      const float s2 = Dreg[jt][r][2];
      const float s3 = Dreg[jt][r][3];
      const float p0 = fexp2((uu[r] + W.x) - s0);
      const float p1 = fexp2((uu[r] + W.y) - s1);
      const float p2 = fexp2((uu[r] + W.z) - s2);
      const float p3 = fexp2((uu[r] + W.w) - s3);
      costacc = fmaf(p0, s0, costacc);
      costacc = fmaf(p1, s1, costacc);
      costacc = fmaf(p2, s2, costacc);
      costacc = fmaf(p3, s3, costacc);
      const size_t off = (size_t)(row0 + r) * NPTS + j;
      f4u pv; pv.x = p0; pv.y = p1; pv.z = p2; pv.w = p3;
      f4u cv; cv.x = s0 * INV_SL; cv.y = s1 * INV_SL;
      cv.z = s2 * INV_SL; cv.w = s3 * INV_SL;
      *(f4u*)(pi + off) = pv;   // out+1 base is 4B-aligned; f4u is aligned(4)
      *(f4u*)(cm + off) = cv;
    }
  }
  const float cw = wave_sum64(costacc);
  if (lane == 0) sCost[wv] = cw;
  __syncthreads();
  if (tid == 0) {
    float c = 0.f;
#pragma unroll
    for (int w = 0; w < WPB; ++w) c += sCost[w];
    atomicAdd(out, c * INV_SL);
  }
}

__global__ void sinkhorn_init(float* __restrict__ v, int* __restrict__ bar,
                              float* __restrict__ out) {
  const int i = blockIdx.x * blockDim.x + threadIdx.x;
  if (i < NPTS) coh_store(v + i, 0.f);
  if (i < BAR_INTS)
    __hip_atomic_store(bar + i, 0, __ATOMIC_RELAXED, __HIP_MEMORY_SCOPE_AGENT);
  if (i == 0) out[0] = 0.f;
}

extern "C" void kernel_launch(void* const* d_in, const int* in_sizes, int n_in,
                              void* d_out, int out_size, void* d_ws, size_t ws_size,
                              hipStream_t stream) {
  const float* x = (const float*)d_in[0];
  const float* y = (const float*)d_in[1];
  float* u = (float*)d_ws;
  float* v = u + NPTS;
  int* bar = (int*)(v + NPTS);
  float* out = (float*)d_out;

  sinkhorn_init<<<dim3(16), dim3(256), 0, stream>>>(v, bar, out);

  void* args[6];
  args[0] = (void*)&x;
  args[1] = (void*)&y;
  args[2] = (void*)&u;
  args[3] = (void*)&v;
  args[4] = (void*)&out;
  args[5] = (void*)&bar;
  hipLaunchCooperativeKernel((void*)sinkhorn_main, dim3(NBLK), dim3(TPB),
                             args, 0, stream);
}

// Round 8
// 714.188 us; speedup vs baseline: 1.3119x; 1.3119x over previous
//
#include <hip/hip_runtime.h>

// Sinkhorn, N=4096, D=2, P=1, eps=0.1, 50 iters — persistent cooperative kernel.
// Round-11: round-10's direct-leaf-poll REVERTED (577 -> 823 us: 256 pollers
// issuing coherent loads against the 16 lines being RMW'd by arrivals
// serialize at the MALL — the round-8 separation of RMW lines (arrival) from
// read-only release lines (leafdone) is load-bearing). Kept from round-10:
//  - fused combine: wave 0 combines + coh_stores after the post-reduce sync;
//    tid 0 drains with wave-level vmcnt(0), arrives, polls; one fewer
//    block-wide __syncthreads per phase than round-8.
//  - u = A_LOGMU - INV_SL*log2(S) identity.
// Barrier protocol itself: verbatim round-8 (leaf RMW -> winner stores
// leafdone[leaf]=k -> all poll 16 leafdone lines, monotone, ABA-free).

#define NPTS    4096
#define EPS_F   0.1f
#define S_L2E   14.426950408889634f     /* log2(e)/eps */
#define INV_SL  0.0693147180559945f     /* 1/S_L2E = eps*ln2 */
#define A_LOGMU (-0.8317725207f)        /* eps * ln(1/N + 1e-8) */
#define N_ITER  50
#define NBLK    256
#define TPB     1024
#define WPB     (TPB / 64)              /* 16 waves/block */
#define RPW     2                       /* rows per wave (wave-pair shares rows) */
#define HALFC   2048                    /* columns per wave (pair splits 4096) */
#define NJT     (HALFC / 256)           /* 8 j-tiles of 64 lanes x 4 cols */
#define NLEAF   16
#define BSTRIDE 64                      /* ints between barrier words = 256 B */
/* layout: leaf i at i*BSTRIDE (i<16); [16] unused; leafdone r at (17+r)*BSTRIDE */
#define BAR_INTS ((NLEAF + 1 + NLEAF) * BSTRIDE)

typedef float f4u __attribute__((ext_vector_type(4), aligned(4)));

__device__ __forceinline__ float fexp2(float x) {
#if __has_builtin(__builtin_amdgcn_exp2f)
  return __builtin_amdgcn_exp2f(x);
#else
  float r;
  asm("v_exp_f32 %0, %1" : "=v"(r) : "v"(x));
  return r;
#endif
}

__device__ __forceinline__ float coh_load(const float* p) {
  return __hip_atomic_load(p, __ATOMIC_RELAXED, __HIP_MEMORY_SCOPE_AGENT);
}
__device__ __forceinline__ void coh_store(float* p, float x) {
  __hip_atomic_store(p, x, __ATOMIC_RELAXED, __HIP_MEMORY_SCOPE_AGENT);
}

__device__ __forceinline__ float wave_sum64(float x) {
#pragma unroll
  for (int off = 32; off > 0; off >>= 1) x += __shfl_xor(x, off, 64);
  return x;
}

// Combine + output store + grid barrier, fused. All barrier ops RELAXED AGENT.
// Entry __syncthreads makes sPart visible (and all waves done reading sW).
// tids 0-15 (wave 0) combine and coh_store the block's 16 u/v rows; tid 0
// drains the wave's stores (wave-level vmcnt(0) — same wave, covers all 16),
// RMW-arrives on its leaf line; the leaf winner (old == 16k-1) publishes
// leafdone[leaf] = k; tid 0 then polls the 16 STORE-ONLY leafdone lines
// (min >= k). RMW lines and poll lines are disjoint — pollers never touch
// lines under RMW (round-10 regression root cause). Exit __syncthreads
// releases the block.
__device__ __forceinline__ void combine_store_barrier(
    float (*sPart)[RPW], float* __restrict__ wout, int row0blk, int tid,
    int* __restrict__ bar, int k) {
  __syncthreads();
  if (tid < 16) {
    const int p = tid >> 1, r = tid & 1;
    const float S = sPart[2 * p][r] + sPart[2 * p + 1][r];
    coh_store(wout + row0blk + p * RPW + r, A_LOGMU - INV_SL * __log2f(S));
    if (tid == 0) {
      asm volatile("s_waitcnt vmcnt(0)" ::: "memory");
      const int myleaf = blockIdx.x & (NLEAF - 1);
      const int old = __hip_atomic_fetch_add(bar + myleaf * BSTRIDE, 1,
                                             __ATOMIC_RELAXED,
                                             __HIP_MEMORY_SCOPE_AGENT);
      if (old == NLEAF * k - 1)
        __hip_atomic_store(bar + (NLEAF + 1 + myleaf) * BSTRIDE, k,
                           __ATOMIC_RELAXED, __HIP_MEMORY_SCOPE_AGENT);
      for (;;) {
        int mn = k;
#pragma unroll
        for (int rr = 0; rr < NLEAF; ++rr) {
          const int f = __hip_atomic_load(bar + (NLEAF + 1 + rr) * BSTRIDE,
                                          __ATOMIC_RELAXED,
                                          __HIP_MEMORY_SCOPE_AGENT);
          mn = min(mn, f);
        }
        if (mn >= k) break;
        __builtin_amdgcn_s_sleep(1);
      }
    }
  }
  __syncthreads();
}

// Per-phase stage: coherent W load + scale into LDS (coords are persistent).
__device__ __forceinline__ void stageW(const float* __restrict__ win,
                                       float* __restrict__ sW, int tid) {
  const int c = tid * 4;
  const float w0 = coh_load(win + c + 0), w1 = coh_load(win + c + 1);
  const float w2 = coh_load(win + c + 2), w3 = coh_load(win + c + 3);
  float4 W;
  W.x = w0 * S_L2E;  W.y = w1 * S_L2E;  W.z = w2 * S_L2E;  W.w = w3 * S_L2E;
  *(float4*)(sW + c) = W;
  __syncthreads();
}

// One-time coord stage: scaled column coords into LDS (4 cols/thread).
__device__ __forceinline__ void stageCoords(const float* __restrict__ colp,
                                            float* __restrict__ sC0,
                                            float* __restrict__ sC1, int tid) {
  const int c = tid * 4;
  const float4 a = ((const float4*)colp)[(c >> 1) + 0];  // (x0,y0,x1,y1)
  const float4 b = ((const float4*)colp)[(c >> 1) + 1];  // (x2,y2,x3,y3)
  float4 C0, C1;
  C0.x = a.x * S_L2E; C0.y = a.z * S_L2E; C0.z = b.x * S_L2E; C0.w = b.z * S_L2E;
  C1.x = a.y * S_L2E; C1.y = a.w * S_L2E; C1.z = b.y * S_L2E; C1.w = b.w * S_L2E;
  *(float4*)(sC0 + c) = C0;
  *(float4*)(sC1 + c) = C1;
}

// u-phase: W from LDS, D from Dreg (compiler may remat — measured-neutral).
__device__ __forceinline__ void phaseU(const float* __restrict__ sW,
                                       const float (&Dreg)[NJT][RPW][4],
                                       float (*sPart)[RPW],
                                       float* __restrict__ wout,
                                       int row0blk, int wv, int lane, int tid,
                                       int base, int* __restrict__ bar, int k) {
  float acc0 = 0.f, acc1 = 0.f;
#pragma unroll
  for (int jt = 0; jt < NJT; ++jt) {
    const int j = base + jt * 256;
    const float4 W = *(const float4*)(sW + j);
    acc0 += (fexp2(W.x - Dreg[jt][0][0]) + fexp2(W.y - Dreg[jt][0][1])) +
            (fexp2(W.z - Dreg[jt][0][2]) + fexp2(W.w - Dreg[jt][0][3]));
    acc1 += (fexp2(W.x - Dreg[jt][1][0]) + fexp2(W.y - Dreg[jt][1][1])) +
            (fexp2(W.z - Dreg[jt][1][2]) + fexp2(W.w - Dreg[jt][1][3]));
  }
  const float S0 = wave_sum64(acc0);
  const float S1 = wave_sum64(acc1);
  if (lane == 0) { sPart[wv][0] = S0; sPart[wv][1] = S1; }
  combine_store_barrier(sPart, wout, row0blk, tid, bar, k);
}

// v-phase: distances recomputed from persistent x-coords in LDS.
__device__ __forceinline__ void phaseV(const float* __restrict__ rx,
                                       const float* __restrict__ ry,
                                       const float* __restrict__ sW,
                                       const float* __restrict__ sC0,
                                       const float* __restrict__ sC1,
                                       float (*sPart)[RPW],
                                       float* __restrict__ wout,
                                       int row0blk, int wv, int lane, int tid,
                                       int base, int* __restrict__ bar, int k) {
  float acc0 = 0.f, acc1 = 0.f;
#pragma unroll
  for (int jt = 0; jt < NJT; ++jt) {
    const int j = base + jt * 256;
    const float4 W  = *(const float4*)(sW + j);
    const float4 C0 = *(const float4*)(sC0 + j);
    const float4 C1 = *(const float4*)(sC1 + j);
    {
      const float a0 = (W.x - fabsf(rx[0] - C0.x)) - fabsf(ry[0] - C1.x);
      const float a1 = (W.y - fabsf(rx[0] - C0.y)) - fabsf(ry[0] - C1.y);
      const float a2 = (W.z - fabsf(rx[0] - C0.z)) - fabsf(ry[0] - C1.z);
      const float a3 = (W.w - fabsf(rx[0] - C0.w)) - fabsf(ry[0] - C1.w);
      acc0 += (fexp2(a0) + fexp2(a1)) + (fexp2(a2) + fexp2(a3));
    }
    {
      const float a0 = (W.x - fabsf(rx[1] - C0.x)) - fabsf(ry[1] - C1.x);
      const float a1 = (W.y - fabsf(rx[1] - C0.y)) - fabsf(ry[1] - C1.y);
      const float a2 = (W.z - fabsf(rx[1] - C0.z)) - fabsf(ry[1] - C1.z);
      const float a3 = (W.w - fabsf(rx[1] - C0.w)) - fabsf(ry[1] - C1.w);
      acc1 += (fexp2(a0) + fexp2(a1)) + (fexp2(a2) + fexp2(a3));
    }
  }
  const float S0 = wave_sum64(acc0);
  const float S1 = wave_sum64(acc1);
  if (lane == 0) { sPart[wv][0] = S0; sPart[wv][1] = S1; }
  combine_store_barrier(sPart, wout, row0blk, tid, bar, k);
}

__global__ void __launch_bounds__(TPB, 4)
sinkhorn_main(const float* __restrict__ x, const float* __restrict__ y,
              float* __restrict__ u, float* __restrict__ v,
              float* __restrict__ out, int* __restrict__ bar) {
  __shared__ float sW[NPTS];
  __shared__ float sC0y[NPTS], sC1y[NPTS];    // y cols (u-phase precompute/epi)
  __shared__ float sC0x[NPTS], sC1x[NPTS];    // x cols (v-phase)
  __shared__ float sPart[WPB][RPW];
  __shared__ float sCost[WPB];

  const int tid  = threadIdx.x;
  const int wv   = tid >> 6;
  const int lane = tid & 63;
  const int row0blk = blockIdx.x * (WPB / 2) * RPW;        // 16 rows per block
  const int row0 = row0blk + (wv >> 1) * RPW;              // this wave's rows
  const int base = (wv & 1) * HALFC + lane * 4;

  float rxu[RPW], ryu[RPW], rxv[RPW], ryv[RPW];
#pragma unroll
  for (int r = 0; r < RPW; ++r) {
    const float2 xr = ((const float2*)x)[row0 + r];
    const float2 yr = ((const float2*)y)[row0 + r];
    rxu[r] = xr.x * S_L2E;  ryu[r] = xr.y * S_L2E;
    rxv[r] = yr.x * S_L2E;  ryv[r] = yr.y * S_L2E;
  }

  stageCoords(y, sC0y, sC1y, tid);
  stageCoords(x, sC0x, sC1x, tid);
  __syncthreads();

  // Iteration-invariant scaled distances for this thread's u-phase footprint.
  float Dreg[NJT][RPW][4];
#pragma unroll
  for (int jt = 0; jt < NJT; ++jt) {
    const int j = base + jt * 256;
    const float4 C0 = *(const float4*)(sC0y + j);
    const float4 C1 = *(const float4*)(sC1y + j);
#pragma unroll
    for (int r = 0; r < RPW; ++r) {
      Dreg[jt][r][0] = fabsf(rxu[r] - C0.x) + fabsf(ryu[r] - C1.x);
      Dreg[jt][r][1] = fabsf(rxu[r] - C0.y) + fabsf(ryu[r] - C1.y);
      Dreg[jt][r][2] = fabsf(rxu[r] - C0.z) + fabsf(ryu[r] - C1.z);
      Dreg[jt][r][3] = fabsf(rxu[r] - C0.w) + fabsf(ryu[r] - C1.w);
    }
  }

  int k = 0;
  for (int it = 0; it < N_ITER; ++it) {
    stageW(v, sW, tid);                                     // win = v
    phaseU(sW, Dreg, sPart, u, row0blk, wv, lane, tid, base, bar, ++k);
    stageW(u, sW, tid);                                     // win = u
    phaseV(rxv, ryv, sW, sC0x, sC1x, sPart, v, row0blk, wv, lane, tid, base,
           bar, ++k);
  }
  stageW(v, sW, tid);                                       // final v

  // ---- output: out[0]=cost, out[1..]=pi, out[1+N*N..]=C ----
  float* __restrict__ pi = out + 1;
  float* __restrict__ cm = out + 1 + (size_t)NPTS * NPTS;
  float uu[RPW];
#pragma unroll
  for (int r = 0; r < RPW; ++r) uu[r] = coh_load(u + row0 + r) * S_L2E;

  float costacc = 0.f;
#pragma unroll
  for (int jt = 0; jt < NJT; ++jt) {          // full unroll: Dreg idx static
    const int j = base + jt * 256;
    const float4 W = *(const float4*)(sW + j);
#pragma unroll
    for (int r = 0; r < RPW; ++r) {
      const float s0 = Dreg[jt][r][0];
      const float s1 = Dreg[jt][r][1];
      const float s2 = Dreg[jt][r][2];
      const float s3 = Dreg[jt][r][3];
      const float p0 = fexp2((uu[r] + W.x) - s0);
      const float p1 = fexp2((uu[r] + W.y) - s1);
      const float p2 = fexp2((uu[r] + W.z) - s2);
      const float p3 = fexp2((uu[r] + W.w) - s3);
      costacc = fmaf(p0, s0, costacc);
      costacc = fmaf(p1, s1, costacc);
      costacc = fmaf(p2, s2, costacc);
      costacc = fmaf(p3, s3, costacc);
      const size_t off = (size_t)(row0 + r) * NPTS + j;
      f4u pv; pv.x = p0; pv.y = p1; pv.z = p2; pv.w = p3;
      f4u cv; cv.x = s0 * INV_SL; cv.y = s1 * INV_SL;
      cv.z = s2 * INV_SL; cv.w = s3 * INV_SL;
      *(f4u*)(pi + off) = pv;   // out+1 base is 4B-aligned; f4u is aligned(4)
      *(f4u*)(cm + off) = cv;
    }
  }
  const float cw = wave_sum64(costacc);
  if (lane == 0) sCost[wv] = cw;
  __syncthreads();
  if (tid == 0) {
    float c = 0.f;
#pragma unroll
    for (int w = 0; w < WPB; ++w) c += sCost[w];
    atomicAdd(out, c * INV_SL);
  }
}

__global__ void sinkhorn_init(float* __restrict__ v, int* __restrict__ bar,
                              float* __restrict__ out) {
  const int i = blockIdx.x * blockDim.x + threadIdx.x;
  if (i < NPTS) coh_store(v + i, 0.f);
  if (i < BAR_INTS)
    __hip_atomic_store(bar + i, 0, __ATOMIC_RELAXED, __HIP_MEMORY_SCOPE_AGENT);
  if (i == 0) out[0] = 0.f;
}

extern "C" void kernel_launch(void* const* d_in, const int* in_sizes, int n_in,
                              void* d_out, int out_size, void* d_ws, size_t ws_size,
                              hipStream_t stream) {
  const float* x = (const float*)d_in[0];
  const float* y = (const float*)d_in[1];
  float* u = (float*)d_ws;
  float* v = u + NPTS;
  int* bar = (int*)(v + NPTS);
  float* out = (float*)d_out;

  sinkhorn_init<<<dim3(16), dim3(256), 0, stream>>>(v, bar, out);

  void* args[6];
  args[0] = (void*)&x;
  args[1] = (void*)&y;
  args[2] = (void*)&u;
  args[3] = (void*)&v;
  args[4] = (void*)&out;
  args[5] = (void*)&bar;
  hipLaunchCooperativeKernel((void*)sinkhorn_main, dim3(NBLK), dim3(TPB),
                             args, 0, stream);
}

// Round 10
// 695.384 us; speedup vs baseline: 1.3474x; 1.0270x over previous
//
#include <hip/hip_runtime.h>

// Sinkhorn, N=4096, D=2, P=1, eps=0.1, 50 iters — persistent cooperative kernel.
// Round-13. Diagnosis: rounds 4/5/12 — three UNRELATED protocols — all failed
// with the bit-identical output signature (out0 err 2.275391e-01 = |ref-0|).
// Shared feature: NBLK=512 with ~49KB LDS. Conclusion: the cooperative launch
// was REJECTED (grid > max co-resident at 1 block/CU under the LDS occupancy
// budget) and never ran. All 256-block launches pass.
// This round: split-column kernel — 512 blocks x 1024 thr, each block owns
// 16 rows x ONE half (2048) of the columns. LDS 24.6KB -> 2 blocks/CU even
// under a 64KB budget; launch_bounds(1024,8) caps VGPR at 64 -> 32 waves/CU
// (the occupancy lever rounds 3-11 never reached). Half-row sums go to global
// partial planes (32-bit coh_store — r7: 64-bit atomics bypass MALL, 32-bit
// don't); next stage recombines u = A - eps*ln(p0+p1) inline. Same summation
// order/expressions as round-8 => same trajectory. Verified leaf/leafdone
// barrier (RMW lines disjoint from poll lines), 32 arrivals/leaf.
// GUARD: host occupancy query on the split kernel; if < 2 blocks/CU, launch
// the verbatim round-8 kernel (577us, verified) at 256 blocks instead.

#define NPTS    4096
#define EPS_F   0.1f
#define S_L2E   14.426950408889634f     /* log2(e)/eps */
#define INV_SL  0.0693147180559945f     /* 1/S_L2E = eps*ln2 */
#define A_LOGMU (-0.8317725207f)        /* eps * ln(1/N + 1e-8) */
#define N_ITER  50
#define NLEAF   16
#define BSTRIDE 64                      /* ints between barrier words = 256 B */
/* layout: leaf i at i*BSTRIDE (i<16); [16] unused; leafdone r at (17+r)*BSTRIDE */
#define BAR_INTS ((NLEAF + 1 + NLEAF) * BSTRIDE)

typedef float f4u __attribute__((ext_vector_type(4), aligned(4)));

__device__ __forceinline__ float fexp2(float x) {
#if __has_builtin(__builtin_amdgcn_exp2f)
  return __builtin_amdgcn_exp2f(x);
#else
  float r;
  asm("v_exp_f32 %0, %1" : "=v"(r) : "v"(x));
  return r;
#endif
}

__device__ __forceinline__ float coh_load(const float* p) {
  return __hip_atomic_load(p, __ATOMIC_RELAXED, __HIP_MEMORY_SCOPE_AGENT);
}
__device__ __forceinline__ void coh_store(float* p, float x) {
  __hip_atomic_store(p, x, __ATOMIC_RELAXED, __HIP_MEMORY_SCOPE_AGENT);
}

__device__ __forceinline__ float wave_sum64(float x) {
#pragma unroll
  for (int off = 32; off > 0; off >>= 1) x += __shfl_xor(x, off, 64);
  return x;
}

// Verified barrier (round-8/11): leaf RMW -> winner stores leafdone[leaf]=k ->
// all poll the 16 STORE-ONLY leafdone lines (min >= k, monotone, ABA-free).
// RMW lines and poll lines disjoint (round-10: pollers on RMW'd lines
// serialize at the MALL). arrpl = arrivals per leaf (grid/16), constant-folded.
__device__ __forceinline__ void grid_barrier(int* bar, int k, int arrpl) {
  __syncthreads();
  if (threadIdx.x == 0) {
    const int myleaf = blockIdx.x & (NLEAF - 1);
    const int old = __hip_atomic_fetch_add(bar + myleaf * BSTRIDE, 1,
                                           __ATOMIC_RELAXED,
                                           __HIP_MEMORY_SCOPE_AGENT);
    if (old == arrpl * k - 1)
      __hip_atomic_store(bar + (NLEAF + 1 + myleaf) * BSTRIDE, k,
                         __ATOMIC_RELAXED, __HIP_MEMORY_SCOPE_AGENT);
    for (;;) {
      int mn = k;
#pragma unroll
      for (int rr = 0; rr < NLEAF; ++rr) {
        const int f = __hip_atomic_load(bar + (NLEAF + 1 + rr) * BSTRIDE,
                                        __ATOMIC_RELAXED,
                                        __HIP_MEMORY_SCOPE_AGENT);
        mn = min(mn, f);
      }
      if (mn >= k) break;
      __builtin_amdgcn_s_sleep(1);
    }
  }
  __syncthreads();
}

// ========================== split-column kernel ===========================
#define SBLK  512
#define STPB  1024
#define SARR  (SBLK / NLEAF)            /* 32 arrivals/leaf */
#define SCOLS 2048

// Stage this block's column half: recombine W from the two partial planes
// (w = A - eps*ln(p0+p1), fused log-combine) + coords, scaled, into LDS.
// 2 cols/thread. zero => W=0 (initial v == 0), no partial reads.
__device__ __forceinline__ void stage_half(
    const float* __restrict__ part, const float* __restrict__ colp,
    float* __restrict__ sW, float* __restrict__ sC0, float* __restrict__ sC1,
    int tid, int colbase, bool zero) {
  const int c2 = tid * 2;
  const int g = colbase + c2;
  const float4 a = ((const float4*)colp)[g >> 1];   // (xg, yg, xg1, yg1)
  float w0 = 0.f, w1 = 0.f;
  if (!zero) {
    const float p00 = coh_load(part + g), p01 = coh_load(part + g + 1);
    const float p10 = coh_load(part + NPTS + g);
    const float p11 = coh_load(part + NPTS + g + 1);
    w0 = (A_LOGMU - EPS_F * __logf(p00 + p10)) * S_L2E;
    w1 = (A_LOGMU - EPS_F * __logf(p01 + p11)) * S_L2E;
  }
  float2 W, C0, C1;
  W.x = w0;            W.y = w1;
  C0.x = a.x * S_L2E;  C0.y = a.z * S_L2E;
  C1.x = a.y * S_L2E;  C1.y = a.w * S_L2E;
  *(float2*)(sW + c2)  = W;
  *(float2*)(sC0 + c2) = C0;
  *(float2*)(sC1 + c2) = C1;
  __syncthreads();
}

// One half-iteration: this wave's 1 row x the block's column half.
// Ascending j-tiles — same per-half-row summation order as round-8's waves.
// lane 0 stores the half-row partial; the barrier's entry __syncthreads
// (s_waitcnt vmcnt(0) before s_barrier) drains it before arrival.
__device__ __forceinline__ void phase_half(
    const float rx, const float ry, const float* __restrict__ sW,
    const float* __restrict__ sC0, const float* __restrict__ sC1,
    float* __restrict__ pout, int half, int row, int lane) {
  float acc = 0.f;
#pragma unroll
  for (int jt = 0; jt < 8; ++jt) {
    const int j = lane * 4 + jt * 256;
    const float4 W  = *(const float4*)(sW + j);
    const float4 C0 = *(const float4*)(sC0 + j);
    const float4 C1 = *(const float4*)(sC1 + j);
    const float a0 = (W.x - fabsf(rx - C0.x)) - fabsf(ry - C1.x);
    const float a1 = (W.y - fabsf(rx - C0.y)) - fabsf(ry - C1.y);
    const float a2 = (W.z - fabsf(rx - C0.z)) - fabsf(ry - C1.z);
    const float a3 = (W.w - fabsf(rx - C0.w)) - fabsf(ry - C1.w);
    acc += (fexp2(a0) + fexp2(a1)) + (fexp2(a2) + fexp2(a3));
  }
  const float S = wave_sum64(acc);
  if (lane == 0) coh_store(pout + half * NPTS + row, S);
}

__global__ void __launch_bounds__(STPB, 8)
sinkhorn_split(const float* __restrict__ x, const float* __restrict__ y,
               float* __restrict__ pu, float* __restrict__ pv,
               float* __restrict__ out, int* __restrict__ bar) {
  __shared__ float sW[SCOLS], sC0[SCOLS], sC1[SCOLS];
  __shared__ float sCost[16];

  const int tid  = threadIdx.x;
  const int wv   = tid >> 6;
  const int lane = tid & 63;
  const int half = blockIdx.x & 1;
  const int colbase = half * SCOLS;
  const int row  = (blockIdx.x >> 1) * 16 + wv;            // this wave's row

  const float2 xr = ((const float2*)x)[row];
  const float2 yr = ((const float2*)y)[row];
  const float rxu = xr.x * S_L2E, ryu = xr.y * S_L2E;
  const float rxv = yr.x * S_L2E, ryv = yr.y * S_L2E;

  int k = 0;
  for (int it = 0; it < N_ITER; ++it) {
    stage_half(pv, y, sW, sC0, sC1, tid, colbase, it == 0);
    phase_half(rxu, ryu, sW, sC0, sC1, pu, half, row, lane);
    grid_barrier(bar, ++k, SARR);
    stage_half(pu, x, sW, sC0, sC1, tid, colbase, false);
    phase_half(rxv, ryv, sW, sC0, sC1, pv, half, row, lane);
    grid_barrier(bar, ++k, SARR);
  }
  stage_half(pv, y, sW, sC0, sC1, tid, colbase, false);     // final v

  // ---- output: out[0]=cost, out[1..]=pi, out[1+N*N..]=C ----
  float* __restrict__ pi = out + 1;
  float* __restrict__ cm = out + 1 + (size_t)NPTS * NPTS;
  const float su = coh_load(pu + row) + coh_load(pu + NPTS + row);
  const float uu = (A_LOGMU - EPS_F * __logf(su)) * S_L2E;

  float costacc = 0.f;
#pragma unroll 2
  for (int jt = 0; jt < 8; ++jt) {
    const int j = lane * 4 + jt * 256;
    const float4 W  = *(const float4*)(sW + j);
    const float4 C0 = *(const float4*)(sC0 + j);
    const float4 C1 = *(const float4*)(sC1 + j);
    const float s0 = fabsf(rxu - C0.x) + fabsf(ryu - C1.x);
    const float s1 = fabsf(rxu - C0.y) + fabsf(ryu - C1.y);
    const float s2 = fabsf(rxu - C0.z) + fabsf(ryu - C1.z);
    const float s3 = fabsf(rxu - C0.w) + fabsf(ryu - C1.w);
    const float p0 = fexp2((uu + W.x) - s0);
    const float p1 = fexp2((uu + W.y) - s1);
    const float p2 = fexp2((uu + W.z) - s2);
    const float p3 = fexp2((uu + W.w) - s3);
    costacc = fmaf(p0, s0, costacc);
    costacc = fmaf(p1, s1, costacc);
    costacc = fmaf(p2, s2, costacc);
    costacc = fmaf(p3, s3, costacc);
    const size_t off = (size_t)row * NPTS + colbase + j;
    f4u pvv; pvv.x = p0; pvv.y = p1; pvv.z = p2; pvv.w = p3;
    f4u cv;  cv.x = s0 * INV_SL; cv.y = s1 * INV_SL;
    cv.z = s2 * INV_SL; cv.w = s3 * INV_SL;
    *(f4u*)(pi + off) = pvv;  // out+1 base is 4B-aligned; f4u is aligned(4)
    *(f4u*)(cm + off) = cv;
  }
  const float cw = wave_sum64(costacc);
  if (lane == 0) sCost[wv] = cw;
  __syncthreads();
  if (tid == 0) {
    float c = 0.f;
#pragma unroll
    for (int w = 0; w < 16; ++w) c += sCost[w];
    atomicAdd(out, c * INV_SL);
  }
}

// ===================== fallback: verbatim round-8 kernel ===================
#define FBLK  256
#define FTPB  1024
#define WPB   (FTPB / 64)
#define RPW   2
#define HALFC 2048
#define NJT   (HALFC / 256)
#define FARR  (FBLK / NLEAF)            /* 16 arrivals/leaf */

__device__ __forceinline__ void stageW(const float* __restrict__ win,
                                       float* __restrict__ sW, int tid) {
  const int c = tid * 4;
  const float w0 = coh_load(win + c + 0), w1 = coh_load(win + c + 1);
  const float w2 = coh_load(win + c + 2), w3 = coh_load(win + c + 3);
  float4 W;
  W.x = w0 * S_L2E;  W.y = w1 * S_L2E;  W.z = w2 * S_L2E;  W.w = w3 * S_L2E;
  *(float4*)(sW + c) = W;
  __syncthreads();
}

__device__ __forceinline__ void stageCoords(const float* __restrict__ colp,
                                            float* __restrict__ sC0,
                                            float* __restrict__ sC1, int tid) {
  const int c = tid * 4;
  const float4 a = ((const float4*)colp)[(c >> 1) + 0];
  const float4 b = ((const float4*)colp)[(c >> 1) + 1];
  float4 C0, C1;
  C0.x = a.x * S_L2E; C0.y = a.z * S_L2E; C0.z = b.x * S_L2E; C0.w = b.z * S_L2E;
  C1.x = a.y * S_L2E; C1.y = a.w * S_L2E; C1.z = b.y * S_L2E; C1.w = b.w * S_L2E;
  *(float4*)(sC0 + c) = C0;
  *(float4*)(sC1 + c) = C1;
}

__device__ __forceinline__ void fb_phaseU(const float* __restrict__ sW,
                                          const float (&Dreg)[NJT][RPW][4],
                                          float (*sPart)[RPW],
                                          float* __restrict__ wout,
                                          int row0blk, int wv, int lane,
                                          int tid, int base) {
  float acc0 = 0.f, acc1 = 0.f;
#pragma unroll
  for (int jt = 0; jt < NJT; ++jt) {
    const int j = base + jt * 256;
    const float4 W = *(const float4*)(sW + j);
    acc0 += (fexp2(W.x - Dreg[jt][0][0]) + fexp2(W.y - Dreg[jt][0][1])) +
            (fexp2(W.z - Dreg[jt][0][2]) + fexp2(W.w - Dreg[jt][0][3]));
    acc1 += (fexp2(W.x - Dreg[jt][1][0]) + fexp2(W.y - Dreg[jt][1][1])) +
            (fexp2(W.z - Dreg[jt][1][2]) + fexp2(W.w - Dreg[jt][1][3]));
  }
  const float S0 = wave_sum64(acc0);
  const float S1 = wave_sum64(acc1);
  if (lane == 0) { sPart[wv][0] = S0; sPart[wv][1] = S1; }
  __syncthreads();
  if (tid < 16) {
    const int p = tid >> 1, r = tid & 1;
    const float S = sPart[2 * p][r] + sPart[2 * p + 1][r];
    coh_store(wout + row0blk + p * RPW + r, A_LOGMU - EPS_F * __logf(S));
  }
}

__device__ __forceinline__ void fb_phaseV(const float* __restrict__ rx,
                                          const float* __restrict__ ry,
                                          const float* __restrict__ sW,
                                          const float* __restrict__ sC0,
                                          const float* __restrict__ sC1,
                                          float (*sPart)[RPW],
                                          float* __restrict__ wout,
                                          int row0blk, int wv, int lane,
                                          int tid, int base) {
  float acc0 = 0.f, acc1 = 0.f;
#pragma unroll
  for (int jt = 0; jt < NJT; ++jt) {
    const int j = base + jt * 256;
    const float4 W  = *(const float4*)(sW + j);
    const float4 C0 = *(const float4*)(sC0 + j);
    const float4 C1 = *(const float4*)(sC1 + j);
    {
      const float a0 = (W.x - fabsf(rx[0] - C0.x)) - fabsf(ry[0] - C1.x);
      const float a1 = (W.y - fabsf(rx[0] - C0.y)) - fabsf(ry[0] - C1.y);
      const float a2 = (W.z - fabsf(rx[0] - C0.z)) - fabsf(ry[0] - C1.z);
      const float a3 = (W.w - fabsf(rx[0] - C0.w)) - fabsf(ry[0] - C1.w);
      acc0 += (fexp2(a0) + fexp2(a1)) + (fexp2(a2) + fexp2(a3));
    }
    {
      const float a0 = (W.x - fabsf(rx[1] - C0.x)) - fabsf(ry[1] - C1.x);
      const float a1 = (W.y - fabsf(rx[1] - C0.y)) - fabsf(ry[1] - C1.y);
      const float a2 = (W.z - fabsf(rx[1] - C0.z)) - fabsf(ry[1] - C1.z);
      const float a3 = (W.w - fabsf(rx[1] - C0.w)) - fabsf(ry[1] - C1.w);
      acc1 += (fexp2(a0) + fexp2(a1)) + (fexp2(a2) + fexp2(a3));
    }
  }
  const float S0 = wave_sum64(acc0);
  const float S1 = wave_sum64(acc1);
  if (lane == 0) { sPart[wv][0] = S0; sPart[wv][1] = S1; }
  __syncthreads();
  if (tid < 16) {
    const int p = tid >> 1, r = tid & 1;
    const float S = sPart[2 * p][r] + sPart[2 * p + 1][r];
    coh_store(wout + row0blk + p * RPW + r, A_LOGMU - EPS_F * __logf(S));
  }
}

__global__ void __launch_bounds__(FTPB, 4)
sinkhorn_fallback(const float* __restrict__ x, const float* __restrict__ y,
                  float* __restrict__ u, float* __restrict__ v,
                  float* __restrict__ out, int* __restrict__ bar) {
  __shared__ float sW[NPTS];
  __shared__ float sC0y[NPTS], sC1y[NPTS];
  __shared__ float sC0x[NPTS], sC1x[NPTS];
  __shared__ float sPart[WPB][RPW];
  __shared__ float sCost[WPB];

  const int tid  = threadIdx.x;
  const int wv   = tid >> 6;
  const int lane = tid & 63;
  const int row0blk = blockIdx.x * (WPB / 2) * RPW;
  const int row0 = row0blk + (wv >> 1) * RPW;
  const int base = (wv & 1) * HALFC + lane * 4;

  float rxu[RPW], ryu[RPW], rxv[RPW], ryv[RPW];
#pragma unroll
  for (int r = 0; r < RPW; ++r) {
    const float2 xr = ((const float2*)x)[row0 + r];
    const float2 yr = ((const float2*)y)[row0 + r];
    rxu[r] = xr.x * S_L2E;  ryu[r] = xr.y * S_L2E;
    rxv[r] = yr.x * S_L2E;  ryv[r] = yr.y * S_L2E;
  }

  stageCoords(y, sC0y, sC1y, tid);
  stageCoords(x, sC0x, sC1x, tid);
  __syncthreads();

  float Dreg[NJT][RPW][4];
#pragma unroll
  for (int jt = 0; jt < NJT; ++jt) {
    const int j = base + jt * 256;
    const float4 C0 = *(const float4*)(sC0y + j);
    const float4 C1 = *(const float4*)(sC1y + j);
#pragma unroll
    for (int r = 0; r < RPW; ++r) {
      Dreg[jt][r][0] = fabsf(rxu[r] - C0.x) + fabsf(ryu[r] - C1.x);
      Dreg[jt][r][1] = fabsf(rxu[r] - C0.y) + fabsf(ryu[r] - C1.y);
      Dreg[jt][r][2] = fabsf(rxu[r] - C0.z) + fabsf(ryu[r] - C1.z);
      Dreg[jt][r][3] = fabsf(rxu[r] - C0.w) + fabsf(ryu[r] - C1.w);
    }
  }

  int k = 0;
  for (int it = 0; it < N_ITER; ++it) {
    stageW(v, sW, tid);
    fb_phaseU(sW, Dreg, sPart, u, row0blk, wv, lane, tid, base);
    grid_barrier(bar, ++k, FARR);
    stageW(u, sW, tid);
    fb_phaseV(rxv, ryv, sW, sC0x, sC1x, sPart, v, row0blk, wv, lane, tid, base);
    grid_barrier(bar, ++k, FARR);
  }
  stageW(v, sW, tid);

  float* __restrict__ pi = out + 1;
  float* __restrict__ cm = out + 1 + (size_t)NPTS * NPTS;
  float uu[RPW];
#pragma unroll
  for (int r = 0; r < RPW; ++r) uu[r] = coh_load(u + row0 + r) * S_L2E;

  float costacc = 0.f;
#pragma unroll
  for (int jt = 0; jt < NJT; ++jt) {
    const int j = base + jt * 256;
    const float4 W = *(const float4*)(sW + j);
#pragma unroll
    for (int r = 0; r < RPW; ++r) {
      const float s0 = Dreg[jt][r][0];
      const float s1 = Dreg[jt][r][1];
      const float s2 = Dreg[jt][r][2];
      const float s3 = Dreg[jt][r][3];
      const float p0 = fexp2((uu[r] + W.x) - s0);
      const float p1 = fexp2((uu[r] + W.y) - s1);
      const float p2 = fexp2((uu[r] + W.z) - s2);
      const float p3 = fexp2((uu[r] + W.w) - s3);
      costacc = fmaf(p0, s0, costacc);
      costacc = fmaf(p1, s1, costacc);
      costacc = fmaf(p2, s2, costacc);
      costacc = fmaf(p3, s3, costacc);
      const size_t off = (size_t)(row0 + r) * NPTS + j;
      f4u pvv; pvv.x = p0; pvv.y = p1; pvv.z = p2; pvv.w = p3;
      f4u cv;  cv.x = s0 * INV_SL; cv.y = s1 * INV_SL;
      cv.z = s2 * INV_SL; cv.w = s3 * INV_SL;
      *(f4u*)(pi + off) = pvv;
      *(f4u*)(cm + off) = cv;
    }
  }
  const float cw = wave_sum64(costacc);
  if (lane == 0) sCost[wv] = cw;
  __syncthreads();
  if (tid == 0) {
    float c = 0.f;
#pragma unroll
    for (int w = 0; w < WPB; ++w) c += sCost[w];
    atomicAdd(out, c * INV_SL);
  }
}

// ================================ init ====================================
__global__ void sinkhorn_init(float* __restrict__ buf, int* __restrict__ bar,
                              float* __restrict__ out) {
  const int i = blockIdx.x * blockDim.x + threadIdx.x;
  if (i < 4 * NPTS) coh_store(buf + i, 0.f);   // pu[2 planes] + pv[2 planes]
  if (i < BAR_INTS)
    __hip_atomic_store(bar + i, 0, __ATOMIC_RELAXED, __HIP_MEMORY_SCOPE_AGENT);
  if (i == 0) out[0] = 0.f;
}

extern "C" void kernel_launch(void* const* d_in, const int* in_sizes, int n_in,
                              void* d_out, int out_size, void* d_ws,
                              size_t ws_size, hipStream_t stream) {
  const float* x = (const float*)d_in[0];
  const float* y = (const float*)d_in[1];
  float* pu = (float*)d_ws;               // [2][4096] u half-row partials
  float* pv = pu + 2 * NPTS;              // [2][4096] v half-row partials
  int* bar = (int*)(pv + 2 * NPTS);
  float* out = (float*)d_out;

  sinkhorn_init<<<dim3(64), dim3(256), 0, stream>>>(pu, bar, out);

  int maxb = 0;                            // host-side query, capture-safe
  hipOccupancyMaxActiveBlocksPerMultiprocessor(&maxb, sinkhorn_split, STPB, 0);

  if (maxb >= 2) {                         // 512 co-resident blocks guaranteed
    void* args[6];
    args[0] = (void*)&x;  args[1] = (void*)&y;
    args[2] = (void*)&pu; args[3] = (void*)&pv;
    args[4] = (void*)&out; args[5] = (void*)&bar;
    hipLaunchCooperativeKernel((void*)sinkhorn_split, dim3(SBLK), dim3(STPB),
                               args, 0, stream);
  } else {                                 // verified round-8 path (577 us)
    float* u = pu;                         // plane 0 as u
    float* v = pv;                         // plane 0 as v (zeroed by init)
    void* args[6];
    args[0] = (void*)&x;  args[1] = (void*)&y;
    args[2] = (void*)&u;  args[3] = (void*)&v;
    args[4] = (void*)&out; args[5] = (void*)&bar;
    hipLaunchCooperativeKernel((void*)sinkhorn_fallback, dim3(FBLK),
                               dim3(FTPB), args, 0, stream);
  }
}